// Round 2
// baseline (1022.413 us; speedup 1.0000x reference)
//
#include <hip/hip_runtime.h>
#include <hip/hip_fp16.h>

#define TSTEPS 276
#define NBATCH 32768
#define KDIM   4416   // 276*16
#define NPAD   320    // Wfc rows padded to multiple of 64
#define NOUT   276

typedef _Float16 half8 __attribute__((ext_vector_type(8)));
typedef float    f32x4 __attribute__((ext_vector_type(4)));

__device__ __forceinline__ float fast_sigmoid(float x) {
    float e = __builtin_amdgcn_exp2f(-1.4426950408889634f * x);
    return __builtin_amdgcn_rcpf(1.0f + e);
}
__device__ __forceinline__ float fast_tanh(float x) {
    float e = __builtin_amdgcn_exp2f(2.885390081777927f * x);
    return 1.0f - 2.0f * __builtin_amdgcn_rcpf(1.0f + e);
}

// ---------------- Kernel 1: bidirectional LSTM (row chunk) ----------------
// 8 lanes per (row, dir): lane k owns h_k,c_k and gate rows {k,8+k,16+k,24+k}.
// h broadcast within the 8-lane group via __shfl. Stores h as fp16 into the
// chunk-local H buffer in flat layout [b_local][t][dir*8+k].
__global__ __launch_bounds__(256) void lstm_kernel(
    const float* __restrict__ x,
    const float* __restrict__ Wih_f, const float* __restrict__ Whh_f,
    const float* __restrict__ bih_f, const float* __restrict__ bhh_f,
    const float* __restrict__ Wih_b, const float* __restrict__ Whh_b,
    const float* __restrict__ bih_b, const float* __restrict__ bhh_b,
    int row0, _Float16* __restrict__ Hout)
{
    const int tid = threadIdx.x;
    const int k   = tid & 7;                       // h-index this lane owns
    const int rd  = blockIdx.x * 32 + (tid >> 3);  // chunk-local row-dir id
    const int bl  = rd >> 1;                       // chunk-local row
    const int dir = rd & 1;
    const int bg  = row0 + bl;                     // global row

    const float* Wih = dir ? Wih_b : Wih_f;
    const float* Whh = dir ? Whh_b : Whh_f;
    const float* bih = dir ? bih_b : bih_f;
    const float* bhh = dir ? bhh_b : bhh_f;

    float Wk[4][8], Wi0[4], Wi1[4], bs[4];
    #pragma unroll
    for (int g = 0; g < 4; ++g) {
        int row = g * 8 + k;                       // PyTorch gate order i,f,g,o
        #pragma unroll
        for (int j = 0; j < 8; ++j) Wk[g][j] = Whh[row * 8 + j];
        Wi0[g] = Wih[row * 2 + 0];
        Wi1[g] = Wih[row * 2 + 1];
        bs[g]  = bih[row] + bhh[row];
    }

    const int laneBase = tid & 56;                 // first lane of my 8-group (in-wave)
    const float2* __restrict__ xrow = (const float2*)(x + (size_t)bg * (TSTEPS * 2));
    _Float16* __restrict__ hrow = Hout + (size_t)bl * KDIM + dir * 8 + k;

    float h = 0.0f, c = 0.0f;
    for (int s = 0; s < TSTEPS; ++s) {
        const int tau = dir ? (TSTEPS - 1 - s) : s;
        const float2 xv = xrow[tau];

        float hv[8];
        #pragma unroll
        for (int j = 0; j < 8; ++j) hv[j] = __shfl(h, laneBase + j, 64);

        float a[4];
        #pragma unroll
        for (int g = 0; g < 4; ++g) {
            float acc = fmaf(xv.x, Wi0[g], bs[g]);
            acc = fmaf(xv.y, Wi1[g], acc);
            #pragma unroll
            for (int j = 0; j < 8; ++j) acc = fmaf(Wk[g][j], hv[j], acc);
            a[g] = acc;
        }
        const float ig = fast_sigmoid(a[0]);
        const float fg = fast_sigmoid(a[1]);
        const float gg = fast_tanh(a[2]);
        const float og = fast_sigmoid(a[3]);
        c = fmaf(fg, c, ig * gg);
        h = og * fast_tanh(c);

        hrow[tau * 16] = (_Float16)h;
    }
}

// ---------------- Kernel 2: Wfc fp32 -> fp16, padded to NPAD rows ----------------
__global__ __launch_bounds__(256) void conv_kernel(const float* __restrict__ Wfc,
                                                   _Float16* __restrict__ W2)
{
    int i = blockIdx.x * 256 + threadIdx.x;        // over NPAD*KDIM
    if (i < NPAD * KDIM) {
        int n = i / KDIM;
        W2[i] = (n < NOUT) ? (_Float16)Wfc[i] : (_Float16)0.0f;
    }
}

// ---------------- Kernel 3: out[rows,276] = H[rows,4416] * W2^T + bfc ----------------
// Block tile 128(M) x 64(N), wave tile 32x64 (2x4 of 16x16), K-chunk 32.
__global__ __launch_bounds__(256) void gemm_kernel(
    const _Float16* __restrict__ H, const _Float16* __restrict__ W2,
    const float* __restrict__ bfc, float* __restrict__ out)
{
    __shared__ _Float16 As[128][40];   // K-stride padded 32->40: <=2-way banks, rows 16B-aligned
    __shared__ _Float16 Bs[64][40];

    const int tid  = threadIdx.x;
    const int m0   = blockIdx.x * 128;
    const int n0   = blockIdx.y * 64;
    const int wid  = tid >> 6;
    const int lane = tid & 63;
    const int l15  = lane & 15;
    const int l4   = lane >> 4;

    f32x4 acc[2][4] = {};

    const int rA = tid >> 2;           // 0..63
    const int kp = (tid & 3) * 8;      // 0,8,16,24

    for (int k0 = 0; k0 < KDIM; k0 += 32) {
        const _Float16* Ap = H + (size_t)(m0 + rA) * KDIM + k0 + kp;
        int4 va0 = *(const int4*)Ap;
        int4 va1 = *(const int4*)(Ap + (size_t)64 * KDIM);
        int4 vb  = *(const int4*)(W2 + (size_t)(n0 + rA) * KDIM + k0 + kp);
        *(int4*)&As[rA][kp]      = va0;
        *(int4*)&As[rA + 64][kp] = va1;
        *(int4*)&Bs[rA][kp]      = vb;
        __syncthreads();

        half8 af[2], bf[4];
        #pragma unroll
        for (int mi = 0; mi < 2; ++mi)
            af[mi] = *(const half8*)&As[wid * 32 + mi * 16 + l15][l4 * 8];
        #pragma unroll
        for (int ni = 0; ni < 4; ++ni)
            bf[ni] = *(const half8*)&Bs[ni * 16 + l15][l4 * 8];
        #pragma unroll
        for (int mi = 0; mi < 2; ++mi)
            #pragma unroll
            for (int ni = 0; ni < 4; ++ni)
                acc[mi][ni] = __builtin_amdgcn_mfma_f32_16x16x32_f16(
                    af[mi], bf[ni], acc[mi][ni], 0, 0, 0);
        __syncthreads();
    }

    float bv[4];
    #pragma unroll
    for (int ni = 0; ni < 4; ++ni) {
        int n = n0 + ni * 16 + l15;
        bv[ni] = (n < NOUT) ? bfc[n] : 0.0f;
    }
    #pragma unroll
    for (int mi = 0; mi < 2; ++mi) {
        #pragma unroll
        for (int ni = 0; ni < 4; ++ni) {
            int n = n0 + ni * 16 + l15;
            if (n < NOUT) {
                int m = m0 + wid * 32 + mi * 16 + l4 * 4;
                #pragma unroll
                for (int r = 0; r < 4; ++r)
                    out[(size_t)(m + r) * NOUT + n] = acc[mi][ni][r] + bv[ni];
            }
        }
    }
}

extern "C" void kernel_launch(void* const* d_in, const int* in_sizes, int n_in,
                              void* d_out, int out_size, void* d_ws, size_t ws_size,
                              hipStream_t stream) {
    const float* x     = (const float*)d_in[0];
    const float* Wih_f = (const float*)d_in[1];
    const float* Whh_f = (const float*)d_in[2];
    const float* bih_f = (const float*)d_in[3];
    const float* bhh_f = (const float*)d_in[4];
    const float* Wih_b = (const float*)d_in[5];
    const float* Whh_b = (const float*)d_in[6];
    const float* bih_b = (const float*)d_in[7];
    const float* bhh_b = (const float*)d_in[8];
    const float* Wfc   = (const float*)d_in[9];
    const float* bfc   = (const float*)d_in[10];
    float* out = (float*)d_out;

    // Workspace layout: [W2: NPAD*KDIM fp16][H chunk: chunk*KDIM fp16]
    _Float16* W2 = (_Float16*)d_ws;
    size_t h_off = ((size_t)NPAD * KDIM * 2 + 255) & ~(size_t)255;
    size_t avail = (ws_size > h_off) ? (ws_size - h_off) : 0;
    long maxrows = (long)(avail / ((size_t)KDIM * 2));
    int chunk = (int)((maxrows / 128) * 128);      // GEMM M-tile granularity
    if (chunk > NBATCH) chunk = NBATCH;
    if (chunk < 128)    chunk = 128;               // ws_size must cover >= ~4 MB
    _Float16* Hc = (_Float16*)((char*)d_ws + h_off);

    conv_kernel<<<(NPAD * KDIM + 255) / 256, 256, 0, stream>>>(Wfc, W2);

    for (int r0 = 0; r0 < NBATCH; r0 += chunk) {
        int rows = NBATCH - r0; if (rows > chunk) rows = chunk;   // multiple of 128
        lstm_kernel<<<rows / 16, 256, 0, stream>>>(x, Wih_f, Whh_f, bih_f, bhh_f,
                                                   Wih_b, Whh_b, bih_b, bhh_b,
                                                   r0, Hc);
        gemm_kernel<<<dim3(rows / 128, 5), 256, 0, stream>>>(Hc, W2, bfc,
                                                             out + (size_t)r0 * NOUT);
    }
}